// Round 7
// baseline (687.901 us; speedup 1.0000x reference)
//
#include <hip/hip_runtime.h>
#include <math.h>

typedef unsigned short u16;
typedef __attribute__((ext_vector_type(8))) short bf16x8;     // 8 bf16 = 4 VGPRs (MFMA A/B frag)
typedef __attribute__((ext_vector_type(8))) unsigned short u16x8;
typedef __attribute__((ext_vector_type(4))) float f32x4;      // MFMA C/D frag

#define MFMA(a, b, c) __builtin_amdgcn_mfma_f32_16x16x32_bf16((a), (b), (c), 0, 0, 0)

// async global->LDS, 16B per lane; LDS dest = wave-uniform base + lane*16
#define GLOAD_LDS16(g, l)                                                     \
  __builtin_amdgcn_global_load_lds(                                           \
      (const __attribute__((address_space(1))) void*)(g),                     \
      (__attribute__((address_space(3))) void*)(l), 16, 0, 0)

__device__ __forceinline__ float bf2f(u16 u) {
  union { unsigned int i; float f; } x; x.i = ((unsigned int)u) << 16; return x.f;
}
__device__ __forceinline__ u16 f2bf(float f) {
  union { float f; unsigned int i; } x; x.f = f;
  unsigned int r = x.i + 0x7FFFu + ((x.i >> 16) & 1u);   // round-to-nearest-even
  return (u16)(r >> 16);
}

// ---------------------------------------------------------------------------
// Dtype probes, one launch: flag[i]=1 bf16, 0 fp32 (rounds 1-4: fp32).
// ---------------------------------------------------------------------------
__global__ __launch_bounds__(256) void probe_all(const u16* p0, const u16* p1,
                                                 const u16* p2, const u16* p3,
                                                 const u16* p4, const u16* p5,
                                                 int* __restrict__ flags) {
  const u16* ps[6] = {p0, p1, p2, p3, p4, p5};
  const u16* p = ps[blockIdx.x];
  __shared__ int cnt;
  if (threadIdx.x == 0) cnt = 0;
  __syncthreads();
  const u16 u = p[threadIdx.x * 2];
  const int e = (u >> 7) & 0xFF;
  atomicAdd(&cnt, (e >= 110 && e <= 135) ? 1 : 0);
  __syncthreads();
  if (threadIdx.x == 0) flags[blockIdx.x] = (cnt > 128) ? 1 : 0;
}

// Canonicalize an input buffer to bf16 (8 elems/thread).
__global__ __launch_bounds__(256) void convert_to_bf16(const void* __restrict__ in,
                                                       u16* __restrict__ out, int n8,
                                                       const int* __restrict__ flag) {
  const int i = blockIdx.x * 256 + threadIdx.x;
  if (i >= n8) return;
  if (*flag) {
    ((u16x8*)out)[i] = ((const u16x8*)in)[i];
  } else {
    const float* f = (const float*)in + (size_t)i * 8;
    u16x8 r;
#pragma unroll
    for (int j = 0; j < 8; ++j) r[j] = f2bf(f[j]);
    ((u16x8*)out)[i] = r;
  }
}

// mexp[i] = (1 - mask[i]) * -1e9
__global__ __launch_bounds__(256) void build_mexp(const void* __restrict__ mask,
                                                  const int* __restrict__ mflag,
                                                  float* __restrict__ mexp, int n) {
  const int i = blockIdx.x * 256 + threadIdx.x;
  if (i >= n) return;
  const float m = *mflag ? bf2f(((const u16*)mask)[i]) : ((const float*)mask)[i];
  mexp[i] = (1.0f - m) * -1e9f;
}

// ---------------------------------------------------------------------------
// GEMM v3: C[M,N] = A[M,K] @ B[N,K]^T, bf16 in. 128x128 tile, BK=64,
// global_load_lds width-16 staging (m97 ladder step), XOR-swizzled unpadded
// LDS: row = 8 chunks of 16B; global chunk c stored at chunk c^(r&7).
// Frag read for k-chunk c of row r: &lds[r*64 + ((c)^(r&7))*8].
// mode 0: dst bf16 [B,H,S,D]  mode 1: dst bf16 [B,H,D,S]  mode 2: fp32 [M,N]
// ---------------------------------------------------------------------------
__global__ __launch_bounds__(256) void gemm_bt(const u16* __restrict__ A,
                                               const u16* __restrict__ B,
                                               void* __restrict__ dst,
                                               int K, int mode) {
  __shared__ u16 As[128 * 64];   // 16 KB
  __shared__ u16 Bs[128 * 64];   // 16 KB
  const int tid  = threadIdx.x;
  const int wave = tid >> 6, lane = tid & 63;
  const int quad = lane >> 4, m16 = lane & 15;
  const int wm = (wave >> 1) * 64, wn = (wave & 1) * 64;
  const size_t bi = (size_t)blockIdx.y * 128;
  const size_t bj = (size_t)blockIdx.x * 128;

  f32x4 acc[4][4];
  const f32x4 fz = {0.f, 0.f, 0.f, 0.f};
#pragma unroll
  for (int i = 0; i < 4; ++i)
#pragma unroll
    for (int j = 0; j < 4; ++j) acc[i][j] = fz;

  // per-wave staging descriptors: 4 chunks A + 4 chunks B, fixed across K
  const u16* gA[4]; const u16* gB[4]; u16* lA[4]; u16* lB[4];
#pragma unroll
  for (int j = 0; j < 4; ++j) {
    const int t  = (wave * 4 + j) * 64 + lane;   // linear chunk id in tile
    const int r  = t >> 3;                       // tile row
    const int cs = t & 7;                        // stored (swizzled) chunk
    const int c  = cs ^ (r & 7);                 // global chunk
    gA[j] = A + (bi + r) * (size_t)K + c * 8;
    gB[j] = B + (bj + r) * (size_t)K + c * 8;
    lA[j] = &As[(size_t)t * 8];
    lB[j] = &Bs[(size_t)t * 8];
  }

  for (int k0 = 0; k0 < K; k0 += 64) {
#pragma unroll
    for (int j = 0; j < 4; ++j) GLOAD_LDS16(gA[j] + k0, lA[j]);
#pragma unroll
    for (int j = 0; j < 4; ++j) GLOAD_LDS16(gB[j] + k0, lB[j]);
    __syncthreads();   // compiler inserts vmcnt(0) drain

    bf16x8 af[2][4], bfv[2][4];
#pragma unroll
    for (int kk = 0; kk < 2; ++kk) {
#pragma unroll
      for (int mt = 0; mt < 4; ++mt) {
        const int m = wm + mt * 16 + m16;
        af[kk][mt] = *(const bf16x8*)&As[m * 64 + ((kk * 4 + quad) ^ (m & 7)) * 8];
      }
#pragma unroll
      for (int nt = 0; nt < 4; ++nt) {
        const int n = wn + nt * 16 + m16;
        bfv[kk][nt] = *(const bf16x8*)&Bs[n * 64 + ((kk * 4 + quad) ^ (n & 7)) * 8];
      }
    }
#pragma unroll
    for (int kk = 0; kk < 2; ++kk)
#pragma unroll
      for (int mt = 0; mt < 4; ++mt)
#pragma unroll
        for (int nt = 0; nt < 4; ++nt)
          acc[mt][nt] = MFMA(af[kk][mt], bfv[kk][nt], acc[mt][nt]);
    __syncthreads();
  }

  // epilogue: C/D layout col=lane&15, row=quad*4+reg (m89/m91-verified)
#pragma unroll
  for (int mt = 0; mt < 4; ++mt) {
#pragma unroll
    for (int nt = 0; nt < 4; ++nt) {
#pragma unroll
      for (int rg = 0; rg < 4; ++rg) {
        const int row = (int)bi + wm + mt * 16 + quad * 4 + rg;  // b*2048+s
        const int col = (int)bj + wn + nt * 16 + m16;            // h*128+d
        const float v = acc[mt][nt][rg];
        if (mode == 2) {
          ((float*)dst)[(size_t)row * 2048 + col] = v;           // FP32 out
        } else {
          const int bb = row >> 11, s = row & 2047, hh = col >> 7, dd = col & 127;
          const size_t idx =
              (mode == 0) ? ((((size_t)bb * 16 + hh) * 2048 + s) * 128 + dd)
                          : ((((size_t)bb * 16 + hh) * 128 + dd) * 2048 + s);
          ((u16*)dst)[idx] = f2bf(v);
        }
      }
    }
  }
}

// ---------------------------------------------------------------------------
// RoPE in-place on Q,K [B,H,S,D=128] (bf16); folds 1/sqrt(128) into Q.
// ---------------------------------------------------------------------------
__global__ __launch_bounds__(256) void rope_kernel(u16* __restrict__ Qr,
                                                   u16* __restrict__ Kr) {
  const int tid = blockIdx.x * 256 + threadIdx.x;   // B*H*S*64 total
  const int j  = tid & 63;
  const int s  = (tid >> 6) & 2047;
  const int bh = tid >> 17;
  const size_t base = ((size_t)bh * 2048 + s) * 128;
  const float freq = __expf(-(float)j * (9.2103403719761836f / 64.0f));
  float sn, cs;
  sincosf((float)s * freq, &sn, &cs);
  const float qs = 0.08838834764831845f;  // 1/sqrt(128)
  const float q1 = bf2f(Qr[base + j]), q2 = bf2f(Qr[base + j + 64]);
  Qr[base + j]      = f2bf((q1 * cs - q2 * sn) * qs);
  Qr[base + j + 64] = f2bf((q2 * cs + q1 * sn) * qs);
  const float k1 = bf2f(Kr[base + j]), k2 = bf2f(Kr[base + j + 64]);
  Kr[base + j]      = f2bf(k1 * cs - k2 * sn);
  Kr[base + j + 64] = f2bf(k2 * cs + k1 * sn);
}

// ---------------------------------------------------------------------------
// Flash v3: as round-6 (128 Q-rows/block, 4 waves x 2 strips, no-max softmax,
// wave-uniform causal branch on strip min row) + REGISTER PREFETCH of the
// next K/V tile: global loads for kt+1 are issued right after the staging
// barrier and stay in flight across the whole compute phase, removing the
// ~900-cyc HBM latency from the per-iter critical path (round-6 counters:
// MfmaUtil 6%, VALUBusy 9%, HBM 8.5% -> pure latency stall).
// ---------------------------------------------------------------------------
__global__ __launch_bounds__(256, 3) void flash_attn(const u16* __restrict__ Q,
                                                     const u16* __restrict__ Kg,
                                                     const u16* __restrict__ Vg,
                                                     const float* __restrict__ mexp_g,
                                                     u16* __restrict__ ctx) {
  const int S = 2048, D = 128;
  __shared__ u16 Kt[64 * 132];
  __shared__ u16 Vt[128 * 68];
  __shared__ u16 Pt[128 * 68];
  const int tid  = threadIdx.x;
  const int wave = tid >> 6, lane = tid & 63;
  const int quad = lane >> 4, m16 = lane & 15;
  const int qtile = 15 - (int)blockIdx.x;   // heavy blocks first
  const int q0 = qtile * 128;
  const int bh = blockIdx.y;
  const int b = bh >> 4, h = bh & 15;
  const size_t baseQK = (size_t)bh * S * D;
  const size_t baseV  = (size_t)bh * D * S;

  // Q A-frags from global (once per block). A-frag: m=lane&15, k=quad*8+j.
  bf16x8 qf[2][4];
#pragma unroll
  for (int st = 0; st < 2; ++st)
#pragma unroll
    for (int kb = 0; kb < 4; ++kb)
      qf[st][kb] = *(const bf16x8*)&Q[baseQK +
          (size_t)(q0 + wave * 32 + st * 16 + m16) * D + kb * 32 + quad * 8];

  float li[2][4] = {{0.f, 0.f, 0.f, 0.f}, {0.f, 0.f, 0.f, 0.f}};
  f32x4 oacc[2][8];
  const f32x4 fz = {0.f, 0.f, 0.f, 0.f};
#pragma unroll
  for (int st = 0; st < 2; ++st)
#pragma unroll
    for (int dt = 0; dt < 8; ++dt) oacc[st][dt] = fz;

  u16x8 kpre[4], vpre[4];
  auto issue_loads = [&](int k0) {
#pragma unroll
    for (int i = 0; i < 4; ++i) {
      const int id = tid + i * 256;
      const int r = id >> 4, c = id & 15;
      kpre[i] = *(const u16x8*)&Kg[baseQK + (size_t)(k0 + r) * D + c * 8];
    }
#pragma unroll
    for (int i = 0; i < 4; ++i) {
      const int id = tid + i * 256;
      const int d = id >> 3, c = id & 7;
      vpre[i] = *(const u16x8*)&Vg[baseV + (size_t)d * S + k0 + c * 8];
    }
  };

  const int ktmax = 2 * qtile + 1;
  issue_loads(0);
  for (int kt = 0; kt <= ktmax; ++kt) {
    const int k0 = kt * 64;
    // commit prefetched tile to LDS
#pragma unroll
    for (int i = 0; i < 4; ++i) {
      const int id = tid + i * 256;
      const int r = id >> 4, c = id & 15;
      *(u16x8*)&Kt[r * 132 + c * 8] = kpre[i];
    }
#pragma unroll
    for (int i = 0; i < 4; ++i) {
      const int id = tid + i * 256;
      const int d = id >> 3, c = id & 7;
      *(u16x8*)&Vt[d * 68 + c * 8] = vpre[i];
    }
    __syncthreads();
    if (kt < ktmax) issue_loads(k0 + 64);   // in flight during compute

    // per-column padding-mask additive term (L2-hot)
    float madd[4];
#pragma unroll
    for (int nt = 0; nt < 4; ++nt)
      madd[nt] = mexp_g[b * S + k0 + nt * 16 + m16];

#pragma unroll
    for (int st = 0; st < 2; ++st) {
      // S strip = Q K^T (16 rows x 64 cols, K=128)
      f32x4 sacc[4];
#pragma unroll
      for (int nt = 0; nt < 4; ++nt) sacc[nt] = fz;
#pragma unroll
      for (int nt = 0; nt < 4; ++nt)
#pragma unroll
        for (int kb = 0; kb < 4; ++kb) {
          bf16x8 kf = *(const bf16x8*)&Kt[(nt * 16 + m16) * 132 + kb * 32 + quad * 8];
          sacc[nt] = MFMA(qf[st][kb], kf, sacc[nt]);
        }

      const int R0   = q0 + wave * 32 + st * 16;   // strip min row (uniform)
      const int prow = wave * 32 + st * 16 + quad * 4;
      if (k0 + 63 > R0) {   // tile crosses the diagonal for this strip
#pragma unroll
        for (int rg = 0; rg < 4; ++rg) {
          const int row = R0 + quad * 4 + rg;
          float ps = 0.f;
#pragma unroll
          for (int nt = 0; nt < 4; ++nt) {
            const int col = k0 + nt * 16 + m16;
            const float p = (col > row) ? 0.f : __expf(sacc[nt][rg] + madd[nt]);
            ps += p;
            Pt[(prow + rg) * 68 + nt * 16 + m16] = f2bf(p);
          }
          li[st][rg] += ps;
        }
      } else {
#pragma unroll
        for (int rg = 0; rg < 4; ++rg) {
          float ps = 0.f;
#pragma unroll
          for (int nt = 0; nt < 4; ++nt) {
            const float p = __expf(sacc[nt][rg] + madd[nt]);
            ps += p;
            Pt[(prow + rg) * 68 + nt * 16 + m16] = f2bf(p);
          }
          li[st][rg] += ps;
        }
      }
    }
    // Pt rows are wave-private; DS ops in-order per wave: no barrier needed.

    // O += P @ V
#pragma unroll
    for (int kb = 0; kb < 2; ++kb) {
      bf16x8 pf0 = *(const bf16x8*)&Pt[(wave * 32 + m16) * 68 + kb * 32 + quad * 8];
      bf16x8 pf1 = *(const bf16x8*)&Pt[(wave * 32 + 16 + m16) * 68 + kb * 32 + quad * 8];
#pragma unroll
      for (int dt = 0; dt < 8; ++dt) {
        bf16x8 vf = *(const bf16x8*)&Vt[(dt * 16 + m16) * 68 + kb * 32 + quad * 8];
        oacc[0][dt] = MFMA(pf0, vf, oacc[0][dt]);
        oacc[1][dt] = MFMA(pf1, vf, oacc[1][dt]);
      }
    }
    __syncthreads();   // protect Kt/Vt for next stage
  }

  // epilogue: reduce li across quad lanes, scale, store
#pragma unroll
  for (int st = 0; st < 2; ++st) {
#pragma unroll
    for (int rg = 0; rg < 4; ++rg) {
      float ls = li[st][rg];
#pragma unroll
      for (int mk = 1; mk < 16; mk <<= 1) ls += __shfl_xor(ls, mk, 64);
      const float inv = 1.0f / ls;
      const int srow = q0 + wave * 32 + st * 16 + quad * 4 + rg;
#pragma unroll
      for (int dt = 0; dt < 8; ++dt) {
        const int e = h * 128 + dt * 16 + m16;
        ctx[((size_t)b * S + srow) * 2048 + e] = f2bf(oacc[st][dt][rg] * inv);
      }
    }
  }
}

// ---------------------------------------------------------------------------
extern "C" void kernel_launch(void* const* d_in, const int* in_sizes, int n_in,
                              void* d_out, int out_size, void* d_ws, size_t ws_size,
                              hipStream_t stream) {
  (void)in_sizes; (void)n_in; (void)out_size; (void)ws_size;
  const int Bz = 2, S = 2048, E = 2048, H = 16, M = Bz * S;
  const size_t NX = (size_t)Bz * S * E;   // 8388608
  const size_t NW = (size_t)E * E;        // 4194304
  const size_t NM = (size_t)Bz * S;       // 4096

  // ws layout (~117.5 MB)
  char* ws = (char*)d_ws;
  int*   flags = (int*)ws;                 // 6 ints
  float* mexp  = (float*)(ws + 256);       // 16 KB
  u16* xc  = (u16*)(ws + 256 + 16384);
  u16* Wqc = xc + NX;
  u16* Wkc = Wqc + NW;
  u16* Wvc = Wkc + NW;
  u16* Woc = Wvc + NW;
  u16* Qr  = Woc + NW;                     // [B,H,S,D]
  u16* Kr  = Qr + NX;                      // [B,H,S,D]
  u16* Vt  = Kr + NX;                      // [B,H,D,S]
  u16* ctx = Vt + NX;                      // [B,S,E]

  probe_all<<<6, 256, 0, stream>>>((const u16*)d_in[0], (const u16*)d_in[1],
                                   (const u16*)d_in[2], (const u16*)d_in[3],
                                   (const u16*)d_in[4], (const u16*)d_in[5], flags);

  convert_to_bf16<<<(int)(NX / 8 / 256), 256, 0, stream>>>(d_in[0], xc,  (int)(NX / 8), flags + 0);
  convert_to_bf16<<<(int)(NW / 8 / 256), 256, 0, stream>>>(d_in[2], Wqc, (int)(NW / 8), flags + 2);
  convert_to_bf16<<<(int)(NW / 8 / 256), 256, 0, stream>>>(d_in[3], Wkc, (int)(NW / 8), flags + 3);
  convert_to_bf16<<<(int)(NW / 8 / 256), 256, 0, stream>>>(d_in[4], Wvc, (int)(NW / 8), flags + 4);
  convert_to_bf16<<<(int)(NW / 8 / 256), 256, 0, stream>>>(d_in[5], Woc, (int)(NW / 8), flags + 5);
  build_mexp<<<16, 256, 0, stream>>>(d_in[1], flags + 1, mexp, (int)NM);

  dim3 ggrid(E / 128, M / 128);  // (16, 32)
  gemm_bt<<<ggrid, 256, 0, stream>>>(xc, Wqc, Qr, E, 0);
  gemm_bt<<<ggrid, 256, 0, stream>>>(xc, Wkc, Kr, E, 0);
  gemm_bt<<<ggrid, 256, 0, stream>>>(xc, Wvc, Vt, E, 1);
  rope_kernel<<<(Bz * H * S * 64) / 256, 256, 0, stream>>>(Qr, Kr);
  flash_attn<<<dim3(16, Bz * H), 256, 0, stream>>>(Qr, Kr, Vt, mexp, ctx);
  gemm_bt<<<ggrid, 256, 0, stream>>>(ctx, Woc, d_out, E, 2);
}

// Round 8
// 441.270 us; speedup vs baseline: 1.5589x; 1.5589x over previous
//
#include <hip/hip_runtime.h>
#include <math.h>

typedef unsigned short u16;
typedef __attribute__((ext_vector_type(8))) short bf16x8;     // 8 bf16 = 4 VGPRs (MFMA A/B frag)
typedef __attribute__((ext_vector_type(8))) unsigned short u16x8;
typedef __attribute__((ext_vector_type(4))) float f32x4;      // MFMA C/D frag

#define MFMA(a, b, c) __builtin_amdgcn_mfma_f32_16x16x32_bf16((a), (b), (c), 0, 0, 0)

// async global->LDS, 16B per lane; LDS dest = wave-uniform base + lane*16,
// global source = per-lane VGPR address (gather OK)
#define GLOAD_LDS16(g, l)                                                     \
  __builtin_amdgcn_global_load_lds(                                           \
      (const __attribute__((address_space(1))) void*)(g),                     \
      (__attribute__((address_space(3))) void*)(l), 16, 0, 0)

__device__ __forceinline__ float bf2f(u16 u) {
  union { unsigned int i; float f; } x; x.i = ((unsigned int)u) << 16; return x.f;
}
__device__ __forceinline__ u16 f2bf(float f) {
  union { float f; unsigned int i; } x; x.f = f;
  unsigned int r = x.i + 0x7FFFu + ((x.i >> 16) & 1u);   // round-to-nearest-even
  return (u16)(r >> 16);
}

// ---------------------------------------------------------------------------
// Dtype probes, one launch: flag[i]=1 bf16, 0 fp32 (rounds 1-4: fp32).
// ---------------------------------------------------------------------------
__global__ __launch_bounds__(256) void probe_all(const u16* p0, const u16* p1,
                                                 const u16* p2, const u16* p3,
                                                 const u16* p4, const u16* p5,
                                                 int* __restrict__ flags) {
  const u16* ps[6] = {p0, p1, p2, p3, p4, p5};
  const u16* p = ps[blockIdx.x];
  __shared__ int cnt;
  if (threadIdx.x == 0) cnt = 0;
  __syncthreads();
  const u16 u = p[threadIdx.x * 2];
  const int e = (u >> 7) & 0xFF;
  atomicAdd(&cnt, (e >= 110 && e <= 135) ? 1 : 0);
  __syncthreads();
  if (threadIdx.x == 0) flags[blockIdx.x] = (cnt > 128) ? 1 : 0;
}

// Canonicalize an input buffer to bf16 (8 elems/thread).
__global__ __launch_bounds__(256) void convert_to_bf16(const void* __restrict__ in,
                                                       u16* __restrict__ out, int n8,
                                                       const int* __restrict__ flag) {
  const int i = blockIdx.x * 256 + threadIdx.x;
  if (i >= n8) return;
  if (*flag) {
    ((u16x8*)out)[i] = ((const u16x8*)in)[i];
  } else {
    const float* f = (const float*)in + (size_t)i * 8;
    u16x8 r;
#pragma unroll
    for (int j = 0; j < 8; ++j) r[j] = f2bf(f[j]);
    ((u16x8*)out)[i] = r;
  }
}

// mexp[i] = (1 - mask[i]) * -1e9
__global__ __launch_bounds__(256) void build_mexp(const void* __restrict__ mask,
                                                  const int* __restrict__ mflag,
                                                  float* __restrict__ mexp, int n) {
  const int i = blockIdx.x * 256 + threadIdx.x;
  if (i >= n) return;
  const float m = *mflag ? bf2f(((const u16*)mask)[i]) : ((const float*)mask)[i];
  mexp[i] = (1.0f - m) * -1e9f;
}

// ---------------------------------------------------------------------------
// GEMM v4: C[M,N] = A[M,K] @ B[N,K]^T, bf16 in. 128x128 tile, BK=64,
// DOUBLE-BUFFERED global_load_lds staging, single barrier per K-iter:
//   syncthreads (vmcnt0 drains cur-buf loads) -> issue next-buf loads
//   (in flight across compute) -> compute(cur).
// XOR-swizzled unpadded LDS: chunk c of row r stored at c^(r&7).
// mode 0: dst bf16 [B,H,S,D]  mode 1: dst bf16 [B,H,D,S]  mode 2: fp32 [M,N]
// ---------------------------------------------------------------------------
__global__ __launch_bounds__(256) void gemm_bt(const u16* __restrict__ A,
                                               const u16* __restrict__ B,
                                               void* __restrict__ dst,
                                               int K, int mode) {
  __shared__ u16 As[2][128 * 64];   // 32 KB
  __shared__ u16 Bs[2][128 * 64];   // 32 KB
  const int tid  = threadIdx.x;
  const int wave = tid >> 6, lane = tid & 63;
  const int quad = lane >> 4, m16 = lane & 15;
  const int wm = (wave >> 1) * 64, wn = (wave & 1) * 64;
  const size_t bi = (size_t)blockIdx.y * 128;
  const size_t bj = (size_t)blockIdx.x * 128;

  f32x4 acc[4][4];
  const f32x4 fz = {0.f, 0.f, 0.f, 0.f};
#pragma unroll
  for (int i = 0; i < 4; ++i)
#pragma unroll
    for (int j = 0; j < 4; ++j) acc[i][j] = fz;

  // staging descriptors: 4 chunks A + 4 chunks B per wave, fixed across K
  const u16* gA[4]; const u16* gB[4]; int lofs[4];
#pragma unroll
  for (int j = 0; j < 4; ++j) {
    const int t  = (wave * 4 + j) * 64 + lane;   // linear chunk id in tile
    const int r  = t >> 3;                       // tile row
    const int cs = t & 7;                        // stored (swizzled) chunk
    const int c  = cs ^ (r & 7);                 // global chunk
    gA[j] = A + (bi + r) * (size_t)K + c * 8;
    gB[j] = B + (bj + r) * (size_t)K + c * 8;
    lofs[j] = t * 8;
  }

  // prologue: stage K-tile 0 into buffer 0
#pragma unroll
  for (int j = 0; j < 4; ++j) GLOAD_LDS16(gA[j], &As[0][lofs[j]]);
#pragma unroll
  for (int j = 0; j < 4; ++j) GLOAD_LDS16(gB[j], &Bs[0][lofs[j]]);

  const int nIter = K >> 6;
  for (int it = 0; it < nIter; ++it) {
    __syncthreads();                      // drains cur-buf loads; frees other buf
    if (it + 1 < nIter) {
      const int ko = (it + 1) << 6;
      const int nb = (it + 1) & 1;
#pragma unroll
      for (int j = 0; j < 4; ++j) GLOAD_LDS16(gA[j] + ko, &As[nb][lofs[j]]);
#pragma unroll
      for (int j = 0; j < 4; ++j) GLOAD_LDS16(gB[j] + ko, &Bs[nb][lofs[j]]);
    }
    const int cb = it & 1;

    bf16x8 af[2][4], bfv[2][4];
#pragma unroll
    for (int kk = 0; kk < 2; ++kk) {
#pragma unroll
      for (int mt = 0; mt < 4; ++mt) {
        const int m = wm + mt * 16 + m16;
        af[kk][mt] = *(const bf16x8*)&As[cb][m * 64 + ((kk * 4 + quad) ^ (m & 7)) * 8];
      }
#pragma unroll
      for (int nt = 0; nt < 4; ++nt) {
        const int n = wn + nt * 16 + m16;
        bfv[kk][nt] = *(const bf16x8*)&Bs[cb][n * 64 + ((kk * 4 + quad) ^ (n & 7)) * 8];
      }
    }
#pragma unroll
    for (int kk = 0; kk < 2; ++kk)
#pragma unroll
      for (int mt = 0; mt < 4; ++mt)
#pragma unroll
        for (int nt = 0; nt < 4; ++nt)
          acc[mt][nt] = MFMA(af[kk][mt], bfv[kk][nt], acc[mt][nt]);
  }

  // epilogue: C/D layout col=lane&15, row=quad*4+reg (m89/m91-verified)
#pragma unroll
  for (int mt = 0; mt < 4; ++mt) {
#pragma unroll
    for (int nt = 0; nt < 4; ++nt) {
#pragma unroll
      for (int rg = 0; rg < 4; ++rg) {
        const int row = (int)bi + wm + mt * 16 + quad * 4 + rg;  // b*2048+s
        const int col = (int)bj + wn + nt * 16 + m16;            // h*128+d
        const float v = acc[mt][nt][rg];
        if (mode == 2) {
          ((float*)dst)[(size_t)row * 2048 + col] = v;           // FP32 out
        } else {
          const int bb = row >> 11, s = row & 2047, hh = col >> 7, dd = col & 127;
          const size_t idx =
              (mode == 0) ? ((((size_t)bb * 16 + hh) * 2048 + s) * 128 + dd)
                          : ((((size_t)bb * 16 + hh) * 128 + dd) * 2048 + s);
          ((u16*)dst)[idx] = f2bf(v);
        }
      }
    }
  }
}

// ---------------------------------------------------------------------------
// RoPE in-place on Q,K [B,H,S,D=128] (bf16); folds 1/sqrt(128) into Q.
// ---------------------------------------------------------------------------
__global__ __launch_bounds__(256) void rope_kernel(u16* __restrict__ Qr,
                                                   u16* __restrict__ Kr) {
  const int tid = blockIdx.x * 256 + threadIdx.x;   // B*H*S*64 total
  const int j  = tid & 63;
  const int s  = (tid >> 6) & 2047;
  const int bh = tid >> 17;
  const size_t base = ((size_t)bh * 2048 + s) * 128;
  const float freq = __expf(-(float)j * (9.2103403719761836f / 64.0f));
  float sn, cs;
  sincosf((float)s * freq, &sn, &cs);
  const float qs = 0.08838834764831845f;  // 1/sqrt(128)
  const float q1 = bf2f(Qr[base + j]), q2 = bf2f(Qr[base + j + 64]);
  Qr[base + j]      = f2bf((q1 * cs - q2 * sn) * qs);
  Qr[base + j + 64] = f2bf((q2 * cs + q1 * sn) * qs);
  const float k1 = bf2f(Kr[base + j]), k2 = bf2f(Kr[base + j + 64]);
  Kr[base + j]      = f2bf(k1 * cs - k2 * sn);
  Kr[base + j + 64] = f2bf(k2 * cs + k1 * sn);
}

// ---------------------------------------------------------------------------
// Flash v4: round-6 compute structure (128 Q-rows/block, 4 waves x 2 strips,
// no-max softmax, wave-uniform causal branch on strip min row) with
// DOUBLE-BUFFERED K/V staging via global_load_lds (round-7 VGPR-prefetch
// spilled to scratch: WRITE_SIZE 34->301 MB). Single barrier per K-iter;
// next tile's loads are in flight across the whole compute phase.
// XOR-swizzled unpadded LDS (global_load_lds needs contiguous dest).
// LDS = 2*16 + 2*16 + 16 = 80 KB -> 2 blocks/CU (= grid limit anyway).
// ---------------------------------------------------------------------------
__global__ __launch_bounds__(256, 2) void flash_attn(const u16* __restrict__ Q,
                                                     const u16* __restrict__ Kg,
                                                     const u16* __restrict__ Vg,
                                                     const float* __restrict__ mexp_g,
                                                     u16* __restrict__ ctx) {
  const int S = 2048, D = 128;
  __shared__ u16 Kt[2][64 * 128];   // [buf][key r][d], chunk swz c^(r&7) (c 0..15)
  __shared__ u16 Vt[2][128 * 64];   // [buf][d][key],   chunk swz c^(d&7) (c 0..7)
  __shared__ u16 Pt[128 * 64];      // [row][key],      chunk swz c^(row&7)
  const int tid  = threadIdx.x;
  const int wave = tid >> 6, lane = tid & 63;
  const int quad = lane >> 4, m16 = lane & 15;
  const int qtile = 15 - (int)blockIdx.x;   // heavy blocks first
  const int q0 = qtile * 128;
  const int bh = blockIdx.y;
  const int b = bh >> 4, h = bh & 15;
  const size_t baseQK = (size_t)bh * S * D;
  const size_t baseV  = (size_t)bh * D * S;

  // staging descriptors (4 wave-instructions each for K and V^T tiles)
  const u16* gK[4]; const u16* gV[4]; int lK[4], lV[4];
#pragma unroll
  for (int j = 0; j < 4; ++j) {
    const int t = (wave * 4 + j) * 64 + lane;    // linear 16B-chunk id
    {
      const int r = t >> 4, cs = t & 15;
      const int c = (cs & 8) | ((cs ^ r) & 7);   // global chunk (0..15)
      gK[j] = Kg + baseQK + (size_t)r * D + c * 8;   // + k0*D per tile
      lK[j] = t * 8;
    }
    {
      const int d = t >> 3, cs = t & 7;
      const int c = cs ^ (d & 7);                // global chunk (0..7)
      gV[j] = Vg + baseV + (size_t)d * S + c * 8;    // + k0 per tile
      lV[j] = t * 8;
    }
  }

  // Q A-frags from global (once per block). A-frag: m=lane&15, k=quad*8+j.
  bf16x8 qf[2][4];
#pragma unroll
  for (int st = 0; st < 2; ++st)
#pragma unroll
    for (int kb = 0; kb < 4; ++kb)
      qf[st][kb] = *(const bf16x8*)&Q[baseQK +
          (size_t)(q0 + wave * 32 + st * 16 + m16) * D + kb * 32 + quad * 8];

  float li[2][4] = {{0.f, 0.f, 0.f, 0.f}, {0.f, 0.f, 0.f, 0.f}};
  f32x4 oacc[2][8];
  const f32x4 fz = {0.f, 0.f, 0.f, 0.f};
#pragma unroll
  for (int st = 0; st < 2; ++st)
#pragma unroll
    for (int dt = 0; dt < 8; ++dt) oacc[st][dt] = fz;

  // prologue: stage tile 0 into buffer 0
#pragma unroll
  for (int j = 0; j < 4; ++j) GLOAD_LDS16(gK[j], &Kt[0][lK[j]]);
#pragma unroll
  for (int j = 0; j < 4; ++j) GLOAD_LDS16(gV[j], &Vt[0][lV[j]]);

  const int ktmax = 2 * qtile + 1;
  for (int kt = 0; kt <= ktmax; ++kt) {
    const int k0 = kt * 64;
    const int cb = kt & 1;
    __syncthreads();                 // vmcnt(0): cur-buf loaded; other buf free
    if (kt < ktmax) {
      const int nb = 1 - cb;
#pragma unroll
      for (int j = 0; j < 4; ++j) GLOAD_LDS16(gK[j] + (size_t)(k0 + 64) * D, &Kt[nb][lK[j]]);
#pragma unroll
      for (int j = 0; j < 4; ++j) GLOAD_LDS16(gV[j] + (k0 + 64), &Vt[nb][lV[j]]);
    }

    // per-column padding-mask additive term (L2-hot)
    float madd[4];
#pragma unroll
    for (int nt = 0; nt < 4; ++nt)
      madd[nt] = mexp_g[b * S + k0 + nt * 16 + m16];

#pragma unroll
    for (int st = 0; st < 2; ++st) {
      // S strip = Q K^T (16 rows x 64 cols, K=128)
      f32x4 sacc[4];
#pragma unroll
      for (int nt = 0; nt < 4; ++nt) sacc[nt] = fz;
#pragma unroll
      for (int nt = 0; nt < 4; ++nt)
#pragma unroll
        for (int kb = 0; kb < 4; ++kb) {
          const int c = kb * 4 + quad;
          const int cs = (c & 8) | ((c ^ m16) & 7);
          bf16x8 kf = *(const bf16x8*)&Kt[cb][(nt * 16 + m16) * 128 + cs * 8];
          sacc[nt] = MFMA(qf[st][kb], kf, sacc[nt]);
        }

      const int R0   = q0 + wave * 32 + st * 16;   // strip min row (uniform)
      const int prow = wave * 32 + st * 16 + quad * 4;
      if (k0 + 63 > R0) {   // tile crosses the diagonal for this strip
#pragma unroll
        for (int rg = 0; rg < 4; ++rg) {
          const int row = R0 + quad * 4 + rg;
          const int pr  = prow + rg;
          float ps = 0.f;
#pragma unroll
          for (int nt = 0; nt < 4; ++nt) {
            const int col = k0 + nt * 16 + m16;
            const float p = (col > row) ? 0.f : __expf(sacc[nt][rg] + madd[nt]);
            ps += p;
            const int c = nt * 2 + (m16 >> 3);
            Pt[pr * 64 + ((c ^ pr) & 7) * 8 + (m16 & 7)] = f2bf(p);
          }
          li[st][rg] += ps;
        }
      } else {
#pragma unroll
        for (int rg = 0; rg < 4; ++rg) {
          const int pr = prow + rg;
          float ps = 0.f;
#pragma unroll
          for (int nt = 0; nt < 4; ++nt) {
            const float p = __expf(sacc[nt][rg] + madd[nt]);
            ps += p;
            const int c = nt * 2 + (m16 >> 3);
            Pt[pr * 64 + ((c ^ pr) & 7) * 8 + (m16 & 7)] = f2bf(p);
          }
          li[st][rg] += ps;
        }
      }
    }
    // Pt rows are wave-private; DS ops in-order per wave: no barrier needed.

    // O += P @ V
#pragma unroll
    for (int kb = 0; kb < 2; ++kb) {
      const int c = kb * 4 + quad;
      const int cs = (c ^ m16) & 7;
      bf16x8 pf0 = *(const bf16x8*)&Pt[(wave * 32 + m16) * 64 + cs * 8];
      bf16x8 pf1 = *(const bf16x8*)&Pt[(wave * 32 + 16 + m16) * 64 + cs * 8];
#pragma unroll
      for (int dt = 0; dt < 8; ++dt) {
        bf16x8 vf = *(const bf16x8*)&Vt[cb][(dt * 16 + m16) * 64 + cs * 8];
        oacc[0][dt] = MFMA(pf0, vf, oacc[0][dt]);
        oacc[1][dt] = MFMA(pf1, vf, oacc[1][dt]);
      }
    }
  }

  // epilogue: reduce li across quad lanes, scale, store
#pragma unroll
  for (int st = 0; st < 2; ++st) {
#pragma unroll
    for (int rg = 0; rg < 4; ++rg) {
      float ls = li[st][rg];
#pragma unroll
      for (int mk = 1; mk < 16; mk <<= 1) ls += __shfl_xor(ls, mk, 64);
      const float inv = 1.0f / ls;
      const int srow = q0 + wave * 32 + st * 16 + quad * 4 + rg;
#pragma unroll
      for (int dt = 0; dt < 8; ++dt) {
        const int e = h * 128 + dt * 16 + m16;
        ctx[((size_t)b * S + srow) * 2048 + e] = f2bf(oacc[st][dt][rg] * inv);
      }
    }
  }
}

// ---------------------------------------------------------------------------
extern "C" void kernel_launch(void* const* d_in, const int* in_sizes, int n_in,
                              void* d_out, int out_size, void* d_ws, size_t ws_size,
                              hipStream_t stream) {
  (void)in_sizes; (void)n_in; (void)out_size; (void)ws_size;
  const int Bz = 2, S = 2048, E = 2048, H = 16, M = Bz * S;
  const size_t NX = (size_t)Bz * S * E;   // 8388608
  const size_t NW = (size_t)E * E;        // 4194304
  const size_t NM = (size_t)Bz * S;       // 4096

  // ws layout (~117.5 MB)
  char* ws = (char*)d_ws;
  int*   flags = (int*)ws;                 // 6 ints
  float* mexp  = (float*)(ws + 256);       // 16 KB
  u16* xc  = (u16*)(ws + 256 + 16384);
  u16* Wqc = xc + NX;
  u16* Wkc = Wqc + NW;
  u16* Wvc = Wkc + NW;
  u16* Woc = Wvc + NW;
  u16* Qr  = Woc + NW;                     // [B,H,S,D]
  u16* Kr  = Qr + NX;                      // [B,H,S,D]
  u16* Vt  = Kr + NX;                      // [B,H,D,S]
  u16* ctx = Vt + NX;                      // [B,S,E]

  probe_all<<<6, 256, 0, stream>>>((const u16*)d_in[0], (const u16*)d_in[1],
                                   (const u16*)d_in[2], (const u16*)d_in[3],
                                   (const u16*)d_in[4], (const u16*)d_in[5], flags);

  convert_to_bf16<<<(int)(NX / 8 / 256), 256, 0, stream>>>(d_in[0], xc,  (int)(NX / 8), flags + 0);
  convert_to_bf16<<<(int)(NW / 8 / 256), 256, 0, stream>>>(d_in[2], Wqc, (int)(NW / 8), flags + 2);
  convert_to_bf16<<<(int)(NW / 8 / 256), 256, 0, stream>>>(d_in[3], Wkc, (int)(NW / 8), flags + 3);
  convert_to_bf16<<<(int)(NW / 8 / 256), 256, 0, stream>>>(d_in[4], Wvc, (int)(NW / 8), flags + 4);
  convert_to_bf16<<<(int)(NW / 8 / 256), 256, 0, stream>>>(d_in[5], Woc, (int)(NW / 8), flags + 5);
  build_mexp<<<16, 256, 0, stream>>>(d_in[1], flags + 1, mexp, (int)NM);

  dim3 ggrid(E / 128, M / 128);  // (16, 32)
  gemm_bt<<<ggrid, 256, 0, stream>>>(xc, Wqc, Qr, E, 0);
  gemm_bt<<<ggrid, 256, 0, stream>>>(xc, Wkc, Kr, E, 0);
  gemm_bt<<<ggrid, 256, 0, stream>>>(xc, Wvc, Vt, E, 1);
  rope_kernel<<<(Bz * H * S * 64) / 256, 256, 0, stream>>>(Qr, Kr);
  flash_attn<<<dim3(16, Bz * H), 256, 0, stream>>>(Qr, Kr, Vt, mexp, ctx);
  gemm_bt<<<ggrid, 256, 0, stream>>>(ctx, Woc, d_out, E, 2);
}